// Round 8
// baseline (297.452 us; speedup 1.0000x reference)
//
#include <hip/hip_runtime.h>

// Capsule dynamic routing — b-on-lanes / o-on-waves, READLANE-broadcast weights.
// u_i:(B,N,DI) f32, w:(1,N,NO,DI,DE) f32, bias:(N,NO,1) f32, r=3.
// Identity: logits_r = u_ji . vsum (u_ji includes bias so bias folds in).
// R14 (= R13 resubmit; R7 bench was an infra failure, no signal):
//   every wave-uniform weight-delivery pipe measured so far serializes:
//   scalar K$ s_load chains (R2/R12 ~43/38us), LDS broadcast (R3 56us),
//   same-address vector (R5 105us). New mechanism: per-lane coalesced
//   payload + in-register broadcast. One global_load_dwordx4 per wave =
//   two (n,o) 512B weight blocks (lanes 0..31 hold n, lanes 32..63 hold
//   n+1 -> one load per TWO n-steps), prefetched a pair ahead. Broadcast
//   lane k's float4 via v_readlane (IMMEDIATE lane index — i-loop is
//   pair-unrolled so the index is compile-time) -> SGPR -> FMA scalar
//   operand: pure VALU, zero shared-pipe traffic. 128 readlanes feed 256
//   FMAs per n-step (BPT=2). Everything else = R12 (grid 256, XCD swizzle,
//   LDS softmax exchange, squash unchanged).

#define B    256
#define N    1152
#define NO   10
#define DI   8
#define DE   16
#define NTILE   9
#define NTILES  128    // N / NTILE
#define BPT     2      // b per thread
#define BG      128    // b per block
#define BGS     2      // B / BG
#define THREADS 640    // 10 waves, o = wave id

// ws layout (floats)
#define SP_OFF 0
#define SP_SZ  (NTILES * B * NO * DE)   // 5,242,880
#define VS_OFF (SP_OFF + SP_SZ)
#define VS_SZ  (B * NO * DE)            // 40,960
#define UT_OFF (VS_OFF + VS_SZ)
#define UT_SZ  (2 * N * B * 4)          // 2,359,296 (= B*N*DI)

#define RL(x, l) __int_as_float(__builtin_amdgcn_readlane(__float_as_int(x), (l)))

// ---------------------------------------------------------------------------
// One-time transpose: u (B,N,8) -> ut[((n*2+h)*B + b)*4 + j] = u[b][n][h*4+j]
// ---------------------------------------------------------------------------
__global__ __launch_bounds__(256)
void transpose_kernel(const float* __restrict__ u, float* __restrict__ ut) {
    const int lane = threadIdx.x & 63;
    const int wv   = threadIdx.x >> 6;           // 0..3 -> n offset
    const int n    = blockIdx.x * 4 + wv;
    const int b    = blockIdx.y * 64 + lane;
    const float* up = u + ((size_t)b * N + n) * DI;
    const float4 a0 = *(const float4*)up;
    const float4 a1 = *(const float4*)(up + 4);
    *(float4*)(ut + ((size_t)(n * 2 + 0) * B + b) * 4) = a0;
    *(float4*)(ut + ((size_t)(n * 2 + 1) * B + b) * 4) = a1;
}

// ---------------------------------------------------------------------------
// Routing pass. Grid: 256 blocks x 640 threads (10 waves). 1 block/CU.
// Block id encodes (tile t, b-group g) with same-tile blocks on one XCD:
//   id = (t&7) + 8*((t>>3) + 16*g)
// ---------------------------------------------------------------------------
__global__ __launch_bounds__(THREADS, 3)
void routing_kernel(const float* __restrict__ u,
                    const float* __restrict__ ut,
                    const float* __restrict__ w,
                    const float* __restrict__ bias,
                    const float* __restrict__ vsum,
                    float* __restrict__ s_part,
                    const int has_v,
                    const int use_ut) {
    __shared__ float lgx[2][NO][BG];            // 10 KB double-buffered exchange
    const int tid  = threadIdx.x;
    const int lane = tid & 63;
    const int wv   = __builtin_amdgcn_readfirstlane(tid >> 6);  // 0..9, uniform
    const int o    = wv;                         // one output capsule per wave

    const int id   = blockIdx.x;
    const int xcd  = id & 7;
    const int s    = id >> 3;                    // 0..31
    const int g    = s >> 4;                     // 0..1  (b-group)
    const int t    = ((s & 15) << 3) | xcd;      // 0..127 (tile)
    const int n0   = t * NTILE;
    const int bb   = g * BG;                     // block's b base

    // Per-lane weight payload: lane (half h = lane>>5, k = lane&31) holds
    // float4 #k of the 512B weight block for (npair + h, o).
    const int lhalf = lane >> 5;
    const int lk    = lane & 31;

    // Bias for this wave's o, all 9 n of the tile (scalar path, tiny).
    float bvs[NTILE];
#pragma unroll
    for (int i = 0; i < NTILE; ++i)
        bvs[i] = bias[(n0 + i) * NO + o];

    // vsum fragments for this thread's 2 b values — loop-invariant
    float4 vv[BPT][4];
#pragma unroll
    for (int bi = 0; bi < BPT; ++bi)
#pragma unroll
        for (int eq = 0; eq < 4; ++eq)
            vv[bi][eq] = make_float4(0.f, 0.f, 0.f, 0.f);
    if (has_v) {
#pragma unroll
        for (int bi = 0; bi < BPT; ++bi)
#pragma unroll
            for (int eq = 0; eq < 4; ++eq)
                vv[bi][eq] = *(const float4*)(vsum +
                    ((size_t)(bb + bi * 64 + lane) * NO + o) * DE + eq * 4);
    }

    float4 acc[BPT][4];
#pragma unroll
    for (int bi = 0; bi < BPT; ++bi)
#pragma unroll
        for (int eq = 0; eq < 4; ++eq)
            acc[bi][eq] = make_float4(0.f, 0.f, 0.f, 0.f);

    // Weight pair loader: one coalesced dwordx4 per wave covers n and n+1.
    // Clamp keeps phantom half-loads in bounds (never consumed).
    auto wload = [&](int nbase) -> float4 {
        int nn = nbase + lhalf;
        nn = nn < N ? nn : N - 1;
        return *(const float4*)(w + ((size_t)nn * NO + o) * (DI * DE) + lk * 4);
    };

    // One n-step. LB (0 or 32) and PB (0 or 1) are template params so the
    // readlane source index and the LDS buffer index are compile-time.
    auto step = [&](int i, const float4& wreg, int LB, int PB) {
        const int n = n0 + i;

        // u rows for this thread's 2 b — coalesced from ut, or legacy gather
        float ur[BPT][DI];
#pragma unroll
        for (int bi = 0; bi < BPT; ++bi) {
            const int b = bb + bi * 64 + lane;
            float4 u0, u1;
            if (use_ut) {
                const float* up = ut + ((size_t)(n * 2) * B + b) * 4;
                u0 = *(const float4*)up;
                u1 = *(const float4*)(up + B * 4);
            } else {
                const float* up = u + ((size_t)b * N + n) * DI;
                u0 = *(const float4*)up;
                u1 = *(const float4*)(up + 4);
            }
            ur[bi][0] = u0.x; ur[bi][1] = u0.y; ur[bi][2] = u0.z; ur[bi][3] = u0.w;
            ur[bi][4] = u1.x; ur[bi][5] = u1.y; ur[bi][6] = u1.z; ur[bi][7] = u1.w;
        }

        const float bv = bvs[i];
        float4 uji[BPT][4];
#pragma unroll
        for (int bi = 0; bi < BPT; ++bi)
#pragma unroll
            for (int eq = 0; eq < 4; ++eq)
                uji[bi][eq] = make_float4(bv, bv, bv, bv);
#pragma unroll
        for (int d = 0; d < DI; ++d) {
#pragma unroll
            for (int eq = 0; eq < 4; ++eq) {
                const int src = LB + d * 4 + eq;   // compile-time lane index
                const float w0 = RL(wreg.x, src);
                const float w1 = RL(wreg.y, src);
                const float w2 = RL(wreg.z, src);
                const float w3 = RL(wreg.w, src);
#pragma unroll
                for (int bi = 0; bi < BPT; ++bi) {
                    uji[bi][eq].x += ur[bi][d] * w0;
                    uji[bi][eq].y += ur[bi][d] * w1;
                    uji[bi][eq].z += ur[bi][d] * w2;
                    uji[bi][eq].w += ur[bi][d] * w3;
                }
            }
        }

        float c[BPT];
        if (has_v) {
            // logits: full-e dot in-thread, exchange via LDS for the softmax
#pragma unroll
            for (int bi = 0; bi < BPT; ++bi) {
                float lg = 0.f;
#pragma unroll
                for (int eq = 0; eq < 4; ++eq)
                    lg += uji[bi][eq].x * vv[bi][eq].x + uji[bi][eq].y * vv[bi][eq].y
                        + uji[bi][eq].z * vv[bi][eq].z + uji[bi][eq].w * vv[bi][eq].w;
                lgx[PB][o][bi * 64 + lane] = lg;
            }
            __syncthreads();
#pragma unroll
            for (int bi = 0; bi < BPT; ++bi) {
                float l[NO];
#pragma unroll
                for (int oo = 0; oo < NO; ++oo) l[oo] = lgx[PB][oo][bi * 64 + lane];
                float m = l[0];
#pragma unroll
                for (int oo = 1; oo < NO; ++oo) m = fmaxf(m, l[oo]);
                float sum = 0.f;
#pragma unroll
                for (int oo = 0; oo < NO; ++oo) { l[oo] = __expf(l[oo] - m); sum += l[oo]; }
                c[bi] = l[o] / sum;
            }
            // no second barrier: buffer PB is next written two steps later,
            // separated from these reads by the next step's barrier.
        } else {
            c[0] = 0.1f; c[1] = 0.1f;   // softmax of zeros
        }

#pragma unroll
        for (int bi = 0; bi < BPT; ++bi)
#pragma unroll
            for (int eq = 0; eq < 4; ++eq) {
                acc[bi][eq].x += c[bi] * uji[bi][eq].x;
                acc[bi][eq].y += c[bi] * uji[bi][eq].y;
                acc[bi][eq].z += c[bi] * uji[bi][eq].z;
                acc[bi][eq].w += c[bi] * uji[bi][eq].w;
            }
    };

    // Pair-unrolled main loop: 4 pairs + tail. Prefetch one pair ahead.
    float4 wcur = wload(n0);
#pragma unroll
    for (int p = 0; p < 4; ++p) {
        float4 wnxt = wload(n0 + 2 * p + 2);     // next pair (tail uses half)
        step(2 * p,     wcur, 0,  0);
        step(2 * p + 1, wcur, 32, 1);
        wcur = wnxt;
    }
    step(8, wcur, 0, 0);                          // tail n-step (i = 8)

    // s_part[tile][b][o][e] — same layout squash expects
#pragma unroll
    for (int bi = 0; bi < BPT; ++bi) {
        float* sp = s_part + (((size_t)t * B + bb + bi * 64 + lane) * NO + o) * DE;
#pragma unroll
        for (int eq = 0; eq < 4; ++eq)
            *(float4*)(sp + eq * 4) = acc[bi][eq];
    }
}

// ---------------------------------------------------------------------------
// Squash: s = sum_tiles s_part; v = ||s||/(1+||s||^2)*s; out = v; vsum += v.
// 4 threads/element, 32 tiles each (NTILES=128).
// ---------------------------------------------------------------------------
__global__ __launch_bounds__(256)
void squash_kernel(const float* __restrict__ s_part,
                   float* __restrict__ vsum,
                   float* __restrict__ out,
                   const int accum) {
    const int t0 = blockIdx.x * 256 + threadIdx.x;   // < 4*40960
    const int q  = t0 & 3;
    const int g  = t0 >> 2;

    float s = 0.f;
    const float* sp = s_part + (size_t)(q * 32) * (B * NO * DE) + g;
#pragma unroll 8
    for (int i = 0; i < 32; ++i)
        s += sp[(size_t)i * (B * NO * DE)];
    s += __shfl_xor(s, 1);
    s += __shfl_xor(s, 2);        // full tile sum, all q lanes

    float nsq = s * s;
#pragma unroll
    for (int msk = 4; msk <= 32; msk <<= 1) nsq += __shfl_xor(nsq, msk);
    const float nrm   = sqrtf(nsq);
    const float scale = nrm / (1.f + nsq);
    const float val   = s * scale;

    if (q == 0) {
        out[g]  = val;                               // (B,NO,DE)
        vsum[g] = accum ? (vsum[g] + val) : val;
    }
}

extern "C" void kernel_launch(void* const* d_in, const int* in_sizes, int n_in,
                              void* d_out, int out_size, void* d_ws, size_t ws_size,
                              hipStream_t stream) {
    const float* u    = (const float*)d_in[0];
    const float* w    = (const float*)d_in[1];   // (N,NO,DI,DE)
    const float* bias = (const float*)d_in[2];   // (N,NO)
    // d_in[3] = r, static 3

    float* wsf    = (float*)d_ws;
    float* s_part = wsf + SP_OFF;
    float* vsum   = wsf + VS_OFF;
    float* ut     = wsf + UT_OFF;
    float* out    = (float*)d_out;

    const int use_ut = (ws_size >= (size_t)(SP_SZ + VS_SZ + UT_SZ) * sizeof(float));

    if (use_ut)
        transpose_kernel<<<dim3(N / 4, B / 64), 256, 0, stream>>>(u, ut);

    for (int it = 0; it < 3; ++it) {
        routing_kernel<<<NTILES * BGS, THREADS, 0, stream>>>(
            u, ut, w, bias, vsum, s_part, it > 0, use_ut);
        squash_kernel<<<(4 * B * NO * DE) / 256, 256, 0, stream>>>(
            s_part, vsum, out, it > 0);
    }
}

// Round 9
// 292.597 us; speedup vs baseline: 1.0166x; 1.0166x over previous
//
#include <hip/hip_runtime.h>

// Capsule dynamic routing — b-on-lanes / o-on-waves, REGISTER-RESIDENT weights.
// u_i:(B,N,DI) f32, w:(1,N,NO,DI,DE) f32, bias:(N,NO,1) f32, r=3.
// Identity: logits_r = u_ji . vsum (u_ji includes bias so bias folds in).
// R15: R8's readlane attempt spilled (WRITE 170MB — lambda + runtime-indexed
//   state defeated regalloc; the mechanism was never measured). This round:
//   whole-tile weights live in REGISTERS as per-lane payload — 9n x 128f =
//   1152 f/wave = 18 f/lane = 5 float4/lane, loaded ONCE via 5 coalesced
//   global_load_dwordx4. Broadcast at use via v_readlane with IMMEDIATE
//   lane index (i-loop fully unrolled; every index compile-time; no
//   lambdas). Zero per-n memory traffic: K$/LDS/L1 all out of the loop.
//   launch_bounds(640,2) -> 256-VGPR cap, need ~160 -> no spill possible.
//   Everything else = R12 (grid 256 1 blk/CU, XCD swizzle, BPT=2, LDS
//   softmax exchange, squash unchanged).

#define B    256
#define N    1152
#define NO   10
#define DI   8
#define DE   16
#define NTILE   9
#define NTILES  128    // N / NTILE
#define BPT     2      // b per thread
#define BG      128    // b per block
#define BGS     2      // B / BG
#define THREADS 640    // 10 waves, o = wave id

// ws layout (floats)
#define SP_OFF 0
#define SP_SZ  (NTILES * B * NO * DE)   // 5,242,880
#define VS_OFF (SP_OFF + SP_SZ)
#define VS_SZ  (B * NO * DE)            // 40,960
#define UT_OFF (VS_OFF + VS_SZ)
#define UT_SZ  (2 * N * B * 4)          // 2,359,296 (= B*N*DI)

#define RL(x, l) __int_as_float(__builtin_amdgcn_readlane(__float_as_int(x), (l)))

// ---------------------------------------------------------------------------
// One-time transpose: u (B,N,8) -> ut[((n*2+h)*B + b)*4 + j] = u[b][n][h*4+j]
// ---------------------------------------------------------------------------
__global__ __launch_bounds__(256)
void transpose_kernel(const float* __restrict__ u, float* __restrict__ ut) {
    const int lane = threadIdx.x & 63;
    const int wv   = threadIdx.x >> 6;           // 0..3 -> n offset
    const int n    = blockIdx.x * 4 + wv;
    const int b    = blockIdx.y * 64 + lane;
    const float* up = u + ((size_t)b * N + n) * DI;
    const float4 a0 = *(const float4*)up;
    const float4 a1 = *(const float4*)(up + 4);
    *(float4*)(ut + ((size_t)(n * 2 + 0) * B + b) * 4) = a0;
    *(float4*)(ut + ((size_t)(n * 2 + 1) * B + b) * 4) = a1;
}

// ---------------------------------------------------------------------------
// Routing pass. Grid: 256 blocks x 640 threads (10 waves). 1 block/CU.
// Block id encodes (tile t, b-group g) with same-tile blocks on one XCD:
//   id = (t&7) + 8*((t>>3) + 16*g)
// ---------------------------------------------------------------------------
__global__ __launch_bounds__(THREADS, 2)
void routing_kernel(const float* __restrict__ u,
                    const float* __restrict__ ut,
                    const float* __restrict__ w,
                    const float* __restrict__ bias,
                    const float* __restrict__ vsum,
                    float* __restrict__ s_part,
                    const int has_v,
                    const int use_ut) {
    __shared__ float lgx[2][NO][BG];            // 10 KB double-buffered exchange
    const int tid  = threadIdx.x;
    const int lane = tid & 63;
    const int wv   = __builtin_amdgcn_readfirstlane(tid >> 6);  // 0..9, uniform
    const int o    = wv;                         // one output capsule per wave

    const int id   = blockIdx.x;
    const int xcd  = id & 7;
    const int s    = id >> 3;                    // 0..31
    const int g    = s >> 4;                     // 0..1  (b-group)
    const int t    = ((s & 15) << 3) | xcd;      // 0..127 (tile)
    const int n0   = t * NTILE;
    const int bb   = g * BG;                     // block's b base

    // Per-lane weight payload: for pair p, lane (h = lane>>5, k = lane&31)
    // holds float4 #k of the 512B weight block (n0 + 2p + h, o).
    // 5 float4/lane covers the whole 9-n tile. Loaded once, coalesced.
    const int lhalf = lane >> 5;
    const int lk    = lane & 31;
    float4 wpl[5];
#pragma unroll
    for (int p = 0; p < 5; ++p) {
        int nn = n0 + 2 * p + lhalf;
        nn = nn < N ? nn : N - 1;                // phantom half of tail pair
        wpl[p] = *(const float4*)(w + ((size_t)nn * NO + o) * (DI * DE) + lk * 4);
    }

    // Bias for this wave's o, all 9 n of the tile (scalar path, tiny).
    float bvs[NTILE];
#pragma unroll
    for (int i = 0; i < NTILE; ++i)
        bvs[i] = bias[(n0 + i) * NO + o];

    // vsum fragments for this thread's 2 b values — loop-invariant
    float4 vv[BPT][4];
#pragma unroll
    for (int bi = 0; bi < BPT; ++bi)
#pragma unroll
        for (int eq = 0; eq < 4; ++eq)
            vv[bi][eq] = make_float4(0.f, 0.f, 0.f, 0.f);
    if (has_v) {
#pragma unroll
        for (int bi = 0; bi < BPT; ++bi)
#pragma unroll
            for (int eq = 0; eq < 4; ++eq)
                vv[bi][eq] = *(const float4*)(vsum +
                    ((size_t)(bb + bi * 64 + lane) * NO + o) * DE + eq * 4);
    }

    float4 acc[BPT][4];
#pragma unroll
    for (int bi = 0; bi < BPT; ++bi)
#pragma unroll
        for (int eq = 0; eq < 4; ++eq)
            acc[bi][eq] = make_float4(0.f, 0.f, 0.f, 0.f);

    // Main loop, fully unrolled: every index below is compile-time.
#pragma unroll
    for (int i = 0; i < NTILE; ++i) {
        const int n  = n0 + i;
        const float4 wreg = wpl[i >> 1];         // compile-time payload slot
        const int LB = (i & 1) << 5;             // compile-time lane base
        const int PB = i & 1;                    // compile-time LDS buffer

        // u rows for this thread's 2 b — coalesced from ut, or legacy gather
        float ur[BPT][DI];
#pragma unroll
        for (int bi = 0; bi < BPT; ++bi) {
            const int b = bb + bi * 64 + lane;
            float4 u0, u1;
            if (use_ut) {
                const float* up = ut + ((size_t)(n * 2) * B + b) * 4;
                u0 = *(const float4*)up;
                u1 = *(const float4*)(up + B * 4);
            } else {
                const float* up = u + ((size_t)b * N + n) * DI;
                u0 = *(const float4*)up;
                u1 = *(const float4*)(up + 4);
            }
            ur[bi][0] = u0.x; ur[bi][1] = u0.y; ur[bi][2] = u0.z; ur[bi][3] = u0.w;
            ur[bi][4] = u1.x; ur[bi][5] = u1.y; ur[bi][6] = u1.z; ur[bi][7] = u1.w;
        }

        // u_ji: weights broadcast in-register (v_readlane, immediate index).
        const float bv = bvs[i];
        float4 uji[BPT][4];
#pragma unroll
        for (int bi = 0; bi < BPT; ++bi)
#pragma unroll
            for (int eq = 0; eq < 4; ++eq)
                uji[bi][eq] = make_float4(bv, bv, bv, bv);
#pragma unroll
        for (int d = 0; d < DI; ++d) {
#pragma unroll
            for (int eq = 0; eq < 4; ++eq) {
                const int src = LB + d * 4 + eq;  // compile-time lane index
                const float w0 = RL(wreg.x, src);
                const float w1 = RL(wreg.y, src);
                const float w2 = RL(wreg.z, src);
                const float w3 = RL(wreg.w, src);
#pragma unroll
                for (int bi = 0; bi < BPT; ++bi) {
                    uji[bi][eq].x += ur[bi][d] * w0;
                    uji[bi][eq].y += ur[bi][d] * w1;
                    uji[bi][eq].z += ur[bi][d] * w2;
                    uji[bi][eq].w += ur[bi][d] * w3;
                }
            }
        }

        float c[BPT];
        if (has_v) {
            // logits: full-e dot in-thread, exchange via LDS for the softmax
#pragma unroll
            for (int bi = 0; bi < BPT; ++bi) {
                float lg = 0.f;
#pragma unroll
                for (int eq = 0; eq < 4; ++eq)
                    lg += uji[bi][eq].x * vv[bi][eq].x + uji[bi][eq].y * vv[bi][eq].y
                        + uji[bi][eq].z * vv[bi][eq].z + uji[bi][eq].w * vv[bi][eq].w;
                lgx[PB][o][bi * 64 + lane] = lg;
            }
            __syncthreads();
#pragma unroll
            for (int bi = 0; bi < BPT; ++bi) {
                float l[NO];
#pragma unroll
                for (int oo = 0; oo < NO; ++oo) l[oo] = lgx[PB][oo][bi * 64 + lane];
                float m = l[0];
#pragma unroll
                for (int oo = 1; oo < NO; ++oo) m = fmaxf(m, l[oo]);
                float sum = 0.f;
#pragma unroll
                for (int oo = 0; oo < NO; ++oo) { l[oo] = __expf(l[oo] - m); sum += l[oo]; }
                c[bi] = l[o] / sum;
            }
            // no second barrier: buffer PB is next written at step i+2,
            // separated from these reads by step i+1's barrier.
        } else {
            c[0] = 0.1f; c[1] = 0.1f;   // softmax of zeros
        }

#pragma unroll
        for (int bi = 0; bi < BPT; ++bi)
#pragma unroll
            for (int eq = 0; eq < 4; ++eq) {
                acc[bi][eq].x += c[bi] * uji[bi][eq].x;
                acc[bi][eq].y += c[bi] * uji[bi][eq].y;
                acc[bi][eq].z += c[bi] * uji[bi][eq].z;
                acc[bi][eq].w += c[bi] * uji[bi][eq].w;
            }
    }

    // s_part[tile][b][o][e] — same layout squash expects
#pragma unroll
    for (int bi = 0; bi < BPT; ++bi) {
        float* sp = s_part + (((size_t)t * B + bb + bi * 64 + lane) * NO + o) * DE;
#pragma unroll
        for (int eq = 0; eq < 4; ++eq)
            *(float4*)(sp + eq * 4) = acc[bi][eq];
    }
}

// ---------------------------------------------------------------------------
// Squash: s = sum_tiles s_part; v = ||s||/(1+||s||^2)*s; out = v; vsum += v.
// 4 threads/element, 32 tiles each (NTILES=128).
// ---------------------------------------------------------------------------
__global__ __launch_bounds__(256)
void squash_kernel(const float* __restrict__ s_part,
                   float* __restrict__ vsum,
                   float* __restrict__ out,
                   const int accum) {
    const int t0 = blockIdx.x * 256 + threadIdx.x;   // < 4*40960
    const int q  = t0 & 3;
    const int g  = t0 >> 2;

    float s = 0.f;
    const float* sp = s_part + (size_t)(q * 32) * (B * NO * DE) + g;
#pragma unroll 8
    for (int i = 0; i < 32; ++i)
        s += sp[(size_t)i * (B * NO * DE)];
    s += __shfl_xor(s, 1);
    s += __shfl_xor(s, 2);        // full tile sum, all q lanes

    float nsq = s * s;
#pragma unroll
    for (int msk = 4; msk <= 32; msk <<= 1) nsq += __shfl_xor(nsq, msk);
    const float nrm   = sqrtf(nsq);
    const float scale = nrm / (1.f + nsq);
    const float val   = s * scale;

    if (q == 0) {
        out[g]  = val;                               // (B,NO,DE)
        vsum[g] = accum ? (vsum[g] + val) : val;
    }
}

extern "C" void kernel_launch(void* const* d_in, const int* in_sizes, int n_in,
                              void* d_out, int out_size, void* d_ws, size_t ws_size,
                              hipStream_t stream) {
    const float* u    = (const float*)d_in[0];
    const float* w    = (const float*)d_in[1];   // (N,NO,DI,DE)
    const float* bias = (const float*)d_in[2];   // (N,NO)
    // d_in[3] = r, static 3

    float* wsf    = (float*)d_ws;
    float* s_part = wsf + SP_OFF;
    float* vsum   = wsf + VS_OFF;
    float* ut     = wsf + UT_OFF;
    float* out    = (float*)d_out;

    const int use_ut = (ws_size >= (size_t)(SP_SZ + VS_SZ + UT_SZ) * sizeof(float));

    if (use_ut)
        transpose_kernel<<<dim3(N / 4, B / 64), 256, 0, stream>>>(u, ut);

    for (int it = 0; it < 3; ++it) {
        routing_kernel<<<NTILES * BGS, THREADS, 0, stream>>>(
            u, ut, w, bias, vsum, s_part, it > 0, use_ut);
        squash_kernel<<<(4 * B * NO * DE) / 256, 256, 0, stream>>>(
            s_part, vsum, out, it > 0);
    }
}